// Round 5
// baseline (173.502 us; speedup 1.0000x reference)
//
#include <hip/hip_runtime.h>

#define DEV __device__ __forceinline__

DEV float wsum64(float v) {
    v += __shfl_xor(v, 32);
    v += __shfl_xor(v, 16);
    v += __shfl_xor(v, 8);
    v += __shfl_xor(v, 4);
    v += __shfl_xor(v, 2);
    v += __shfl_xor(v, 1);
    return v;
}
DEV float lrelu(float x, float a) { return x > 0.f ? x : a * x; }
DEV float elu1(float x) { return x > 0.f ? x : (__expf(x) - 1.f); }

// Output GAT layer: 2 distinct node vectors (hub x0, replicated xr), K mult of 4.
DEV float gatOut(const float* __restrict__ x0, const float* __restrict__ xr, int K4,
                 const float* __restrict__ W, const float* __restrict__ a,
                 float nOth, int l) {
    float w0 = 0.f, wr = 0.f;
    const float4* x04 = (const float4*)x0;
    const float4* xr4 = (const float4*)xr;
    for (int kc = 0; kc < K4; ++kc) {
        float4 xv = x04[kc];
        float4 rv = xr4[kc];
        int k = kc * 4;
        float wk0 = W[(k + 0) * 64 + l];
        float wk1 = W[(k + 1) * 64 + l];
        float wk2 = W[(k + 2) * 64 + l];
        float wk3 = W[(k + 3) * 64 + l];
        w0 = __builtin_fmaf(xv.x, wk0, w0);
        w0 = __builtin_fmaf(xv.y, wk1, w0);
        w0 = __builtin_fmaf(xv.z, wk2, w0);
        w0 = __builtin_fmaf(xv.w, wk3, w0);
        wr = __builtin_fmaf(rv.x, wk0, wr);
        wr = __builtin_fmaf(rv.y, wk1, wr);
        wr = __builtin_fmaf(rv.z, wk2, wr);
        wr = __builtin_fmaf(rv.w, wk3, wr);
    }
    float si0 = wsum64(w0 * a[l]);
    float sj0 = wsum64(w0 * a[64 + l]);
    float sjr = wsum64(wr * a[64 + l]);
    float e0 = lrelu(si0 + sj0, 0.2f);
    float er = lrelu(si0 + sjr, 0.2f);
    float m = fmaxf(e0, er);
    float p0 = __expf(e0 - m);
    float pr = __expf(er - m) * nOth;
    float o0 = (p0 * w0 + pr * wr) / (p0 + pr);
    return (elu1(o0) + nOth * elu1(w0)) * (1.f / (nOth + 1.f));
}

// Per-element LDS layout (floats), ELEM_F = 1504 (6016 B):
//  [0..832)    E1 (13x64) during phases 1-2; afterwards:
//     x0s[0..128) xrs[128..256) comb[256..464) h1l[464..528) hm[528..592)
//     xc0[592..624) xcr[624..656) A-vecs[656..784) C-vecs[784..816)
//  scratch inside comb region (dead until phase 4):
//     s1[320..352) s2[352..384) sc1[384..392) sc2[392..400)
//     hdv scores[400..428) cav scores[428..448) road->comb[448..464)
//  [832..1248)  hist 13x16 -> hsh 13x32
//  [1248..1432) curs (184)
//  [1432..1504) hc (9x8, zero-padded)
// Every region touched by exactly ONE wave -> no __syncthreads.
#define ELEM_F 1504

__global__ __launch_bounds__(128, 4) void pred_kernel(
    const float* __restrict__ obs,
    const float* __restrict__ W_se, const float* __restrict__ b_se,
    const float* __restrict__ W_de, const float* __restrict__ b_de,
    const float* __restrict__ Wh1, const float* __restrict__ ah1,
    const float* __restrict__ Wh2, const float* __restrict__ ah2,
    const float* __restrict__ Who, const float* __restrict__ aho,
    const float* __restrict__ Wc1, const float* __restrict__ ac1,
    const float* __restrict__ Wc2, const float* __restrict__ ac2,
    const float* __restrict__ Wco, const float* __restrict__ aco,
    const float* __restrict__ Wl1, const float* __restrict__ bl1,
    const float* __restrict__ Wl2, const float* __restrict__ bl2,
    const float* __restrict__ Wm1, const float* __restrict__ bm1,
    const float* __restrict__ Wm2, const float* __restrict__ bm2,
    float* __restrict__ out)
{
    const int l = threadIdx.x & 63;           // lane
    const int w = threadIdx.x >> 6;           // wave in block = element slot
    const int b = blockIdx.x * 2 + w;         // batch element
    const float* o = obs + (size_t)b * 2064;

    __shared__ float lds[2 * ELEM_F];
    float* S    = lds + w * ELEM_F;
    float* E1   = S;
    float* comb = S + 256;
    float* h1l  = S + 464;
    float* hm   = S + 528;
    float* H    = S + 832;
    float* hsh  = S + 832;
    float* curs = S + 1248;
    float* hc   = S + 1432;

    // ---- phase 0: gather ----
    for (int i = l; i < 208; i += 64) {
        int r = i >> 4, f = i & 15;
        float v = 0.f;
        if (f < 15) {
            int t = f / 3 + 1, ff = f % 3;
            int col = (r == 0) ? (234 + ff) : ((r - 1) * 6 + ff);
            v = o[t * 344 + col];
        }
        H[i] = v;
    }
    for (int i = l; i < 184; i += 64) curs[i] = o[1792 + i];
    // cav nodes (9x8, zero-padded cols 6,7)
    for (int i = l; i < 72; i += 64) {
        int r = i >> 3, f = i & 7;
        float v = 0.f;
        if (f < 6) {
            if (r == 0) {
                int idx = (f < 3) ? (162 + f) : ((f == 3) ? 181 : (175 + f));
                v = curs[idx];
            } else {
                v = curs[(r - 1) * 6 + f];
            }
        }
        hc[i] = v;
    }

    // ---- phase 1: 15->64 lrelu(0.1) ----
    {
        float wv[16];
#pragma unroll
        for (int k = 0; k < 15; ++k) wv[k] = W_se[k * 64 + l];
        wv[15] = 0.f;
        float acc[13];
        float bs = b_se[l];
#pragma unroll
        for (int r = 0; r < 13; ++r) acc[r] = bs;
        const float4* H4 = (const float4*)H;
#pragma unroll
        for (int kc = 0; kc < 4; ++kc) {
#pragma unroll
            for (int r = 0; r < 13; ++r) {
                float4 h = H4[r * 4 + kc];
                acc[r] = __builtin_fmaf(h.x, wv[kc * 4 + 0], acc[r]);
                acc[r] = __builtin_fmaf(h.y, wv[kc * 4 + 1], acc[r]);
                acc[r] = __builtin_fmaf(h.z, wv[kc * 4 + 2], acc[r]);
                acc[r] = __builtin_fmaf(h.w, wv[kc * 4 + 3], acc[r]);
            }
        }
#pragma unroll
        for (int r = 0; r < 13; ++r) E1[r * 64 + l] = lrelu(acc[r], 0.1f);
    }

    // ---- phase 2: 64->32 linear -> hsh ----
    {
        int c = l & 31, r0 = l >> 5;
        float acc[7];
        float bd = b_de[c];
#pragma unroll
        for (int i = 0; i < 7; ++i) acc[i] = bd;
        const float4* E4 = (const float4*)E1;
#pragma unroll 4
        for (int kc = 0; kc < 16; ++kc) {
            int k = kc * 4;
            float w0 = W_de[(k + 0) * 32 + c];
            float w1 = W_de[(k + 1) * 32 + c];
            float w2 = W_de[(k + 2) * 32 + c];
            float w3 = W_de[(k + 3) * 32 + c];
#pragma unroll
            for (int i = 0; i < 7; ++i) {
                int r = r0 + 2 * i;
                float4 e = E4[(r < 13 ? r : 0) * 16 + kc];
                acc[i] = __builtin_fmaf(e.x, w0, acc[i]);
                acc[i] = __builtin_fmaf(e.y, w1, acc[i]);
                acc[i] = __builtin_fmaf(e.z, w2, acc[i]);
                acc[i] = __builtin_fmaf(e.w, w3, acc[i]);
            }
        }
#pragma unroll
        for (int i = 0; i < 7; ++i) {
            int r = r0 + 2 * i;
            if (r < 13) hsh[r * 32 + c] = acc[i];
        }
    }

    // ---- phase 2.5: weight-only attention vectors (E1 now dead) ----
    // A vectors: (W @ a_hi), (W @ a_lo) for Wh1/Wh2 -> S[656..784)
    {
        int c = l & 31;
        const float* Wp = (l < 32) ? Wh1 : Wh2;
        const float* ap = (l < 32) ? ah1 : ah2;
        const float4* Wr4 = (const float4*)(Wp + c * 64);
        const float4* ahi4 = (const float4*)(ap + 64);
        const float4* alo4 = (const float4*)ap;
        float hi = 0.f, lo = 0.f;
#pragma unroll 4
        for (int kc = 0; kc < 16; ++kc) {
            float4 wv = Wr4[kc];
            float4 ha = ahi4[kc];
            float4 la = alo4[kc];
            hi += wv.x * ha.x + wv.y * ha.y + wv.z * ha.z + wv.w * ha.w;
            lo += wv.x * la.x + wv.y * la.y + wv.z * la.z + wv.w * la.w;
        }
        int base = 656 + ((l < 32) ? 0 : 64) + c;
        S[base] = hi;        // A?hi
        S[base + 32] = lo;   // A?lo
    }
    // C vectors for cav GATs -> S[784..816), 8-padded with zeros
    if (l < 32) {
        int c6 = l & 7, g = l >> 3;
        float acc = 0.f;
        if (c6 < 6) {
            const float* Wc = (g < 2) ? Wc1 : Wc2;
            const float* av = (g < 2) ? ac1 : ac2;
            const float* a0 = av + ((g & 1) ? 0 : 16);  // g even: hi (a[16:32])
            const float4* Wr4 = (const float4*)(Wc + c6 * 16);
            const float4* a4 = (const float4*)a0;
#pragma unroll
            for (int kc = 0; kc < 4; ++kc) {
                float4 wv = Wr4[kc];
                float4 aa = a4[kc];
                acc += wv.x * aa.x + wv.y * aa.y + wv.z * aa.z + wv.w * aa.w;
            }
        }
        S[784 + g * 8 + c6] = acc;
    }

    // ---- phase 3a: hdv GAT pair — attention scores (one per lane) ----
    {
        int h = l & 15, gg = l >> 4;
        if (gg < 2 && h < 14) {
            int ridx = (h == 13) ? 0 : h;
            int voff = 656 + gg * 64 + ((h == 13) ? 32 : 0);
            const float4* hr = (const float4*)(S + 832 + ridx * 32);
            const float4* vv = (const float4*)(S + voff);
            float a0 = 0.f, a1 = 0.f, a2 = 0.f, a3 = 0.f;
#pragma unroll
            for (int kc = 0; kc < 8; ++kc) {
                float4 x = hr[kc];
                float4 y = vv[kc];
                a0 = __builtin_fmaf(x.x, y.x, a0);
                a1 = __builtin_fmaf(x.y, y.y, a1);
                a2 = __builtin_fmaf(x.z, y.z, a2);
                a3 = __builtin_fmaf(x.w, y.w, a3);
            }
            S[400 + gg * 14 + h] = (a0 + a1) + (a2 + a3);
        }
    }
    // ---- phase 3b: cav GAT pair — attention scores ----
    {
        int h = l & 15, gg = l >> 4;
        if (gg < 2 && h < 10) {
            int ridx = (h == 9) ? 0 : h;
            int voff = 784 + gg * 16 + ((h == 9) ? 8 : 0);
            const float4* hr = (const float4*)(S + 1432 + ridx * 8);
            const float4* vv = (const float4*)(S + voff);
            float4 x0v = hr[0], x1v = hr[1], y0 = vv[0], y1 = vv[1];
            float d = x0v.x * y0.x + x0v.y * y0.y + x0v.z * y0.z + x0v.w * y0.w
                    + x1v.x * y1.x + x1v.y * y1.y + x1v.z * y1.z + x1v.w * y1.w;
            S[428 + gg * 10 + h] = d;
        }
    }

    // ---- phase 3c: hdv softmax (all lanes, redundant) + s-vectors ----
    {
        const float4* sq = (const float4*)(S + 400);
        float4 q0 = sq[0], q1 = sq[1], q2 = sq[2], q3 = sq[3],
               q4 = sq[4], q5 = sq[5], q6 = sq[6];
        float e1a[13] = {q0.x, q0.y, q0.z, q0.w, q1.x, q1.y, q1.z, q1.w,
                         q2.x, q2.y, q2.z, q2.w, q3.x};
        float si01 = q3.y;
        float e2a[13] = {q3.z, q3.w, q4.x, q4.y, q4.z, q4.w, q5.x, q5.y,
                         q5.z, q5.w, q6.x, q6.y, q6.z};
        float si02 = q6.w;
        float m1 = -1e30f, m2 = -1e30f;
#pragma unroll
        for (int r = 0; r < 13; ++r) {
            e1a[r] = lrelu(si01 + e1a[r], 0.2f);
            e2a[r] = lrelu(si02 + e2a[r], 0.2f);
            m1 = fmaxf(m1, e1a[r]);
            m2 = fmaxf(m2, e2a[r]);
        }
        float den1 = 0.f, den2 = 0.f;
#pragma unroll
        for (int r = 0; r < 13; ++r) {
            e1a[r] = __expf(e1a[r] - m1);
            e2a[r] = __expf(e2a[r] - m2);
            den1 += e1a[r];
            den2 += e2a[r];
        }
        float rd = (l < 32) ? (1.f / den1) : (1.f / den2);
        // s[c] = sum_r pn_r * hsh[r][c]; lanes 0-31 -> GAT1, 32-63 -> GAT2
        {
            int c = l & 31;
            float su = 0.f;
#pragma unroll
            for (int r = 0; r < 13; ++r) {
                float hv = S[832 + r * 32 + c];
                float pr = (l < 32) ? e1a[r] : e2a[r];
                su = __builtin_fmaf(pr, hv, su);
            }
            S[320 + l] = su * rd;   // s1 @320, s2 @352
        }
    }
    // ---- phase 3d: cav softmax + s-vectors ----
    {
        const float4* cq = (const float4*)(S + 428);
        float4 c0 = cq[0], c1 = cq[1], c2 = cq[2], c3 = cq[3], c4 = cq[4];
        float e1a[9] = {c0.x, c0.y, c0.z, c0.w, c1.x, c1.y, c1.z, c1.w, c2.x};
        float sic1 = c2.y;
        float e2a[9] = {c2.z, c2.w, c3.x, c3.y, c3.z, c3.w, c4.x, c4.y, c4.z};
        float sic2 = c4.w;
        float m1 = -1e30f, m2 = -1e30f;
#pragma unroll
        for (int r = 0; r < 9; ++r) {
            e1a[r] = lrelu(sic1 + e1a[r], 0.2f);
            e2a[r] = lrelu(sic2 + e2a[r], 0.2f);
            m1 = fmaxf(m1, e1a[r]);
            m2 = fmaxf(m2, e2a[r]);
        }
        float den1 = 0.f, den2 = 0.f;
#pragma unroll
        for (int r = 0; r < 9; ++r) {
            e1a[r] = __expf(e1a[r] - m1);
            e2a[r] = __expf(e2a[r] - m2);
            den1 += e1a[r];
            den2 += e2a[r];
        }
        if (l < 16) {
            int c = l & 7, gat = l >> 3;
            float su = 0.f;
            if (c < 6) {
#pragma unroll
                for (int r = 0; r < 9; ++r) {
                    float hv = S[1432 + r * 8 + c];
                    float pr = gat ? e2a[r] : e1a[r];
                    su = __builtin_fmaf(pr, hv, su);
                }
                su *= gat ? (1.f / den2) : (1.f / den1);
            }
            S[384 + gat * 8 + c] = su;   // sc1 @384, sc2 @392
        }
    }

    // ---- phase 3e: hdv dual matvec (32->64, x0s/xrs for both GATs) ----
    {
        float o1 = 0.f, w1 = 0.f, o2 = 0.f, w2 = 0.f;
        const float4* s14 = (const float4*)(S + 320);
        const float4* s24 = (const float4*)(S + 352);
        const float4* h04 = (const float4*)(S + 832);   // hsh row 0
#pragma unroll
        for (int kc = 0; kc < 8; ++kc) {
            float4 sa = s14[kc], sb = s24[kc], hz = h04[kc];
            int k = kc * 4;
            float wa0 = Wh1[(k + 0) * 64 + l], wb0 = Wh2[(k + 0) * 64 + l];
            float wa1 = Wh1[(k + 1) * 64 + l], wb1 = Wh2[(k + 1) * 64 + l];
            float wa2 = Wh1[(k + 2) * 64 + l], wb2 = Wh2[(k + 2) * 64 + l];
            float wa3 = Wh1[(k + 3) * 64 + l], wb3 = Wh2[(k + 3) * 64 + l];
            o1 = __builtin_fmaf(sa.x, wa0, o1);
            o1 = __builtin_fmaf(sa.y, wa1, o1);
            o1 = __builtin_fmaf(sa.z, wa2, o1);
            o1 = __builtin_fmaf(sa.w, wa3, o1);
            w1 = __builtin_fmaf(hz.x, wa0, w1);
            w1 = __builtin_fmaf(hz.y, wa1, w1);
            w1 = __builtin_fmaf(hz.z, wa2, w1);
            w1 = __builtin_fmaf(hz.w, wa3, w1);
            o2 = __builtin_fmaf(sb.x, wb0, o2);
            o2 = __builtin_fmaf(sb.y, wb1, o2);
            o2 = __builtin_fmaf(sb.z, wb2, o2);
            o2 = __builtin_fmaf(sb.w, wb3, o2);
            w2 = __builtin_fmaf(hz.x, wb0, w2);
            w2 = __builtin_fmaf(hz.y, wb1, w2);
            w2 = __builtin_fmaf(hz.z, wb2, w2);
            w2 = __builtin_fmaf(hz.w, wb3, w2);
        }
        S[l] = o1;           // x0s[0..64)
        S[64 + l] = o2;      // x0s[64..128)
        S[128 + l] = w1;     // xrs[0..64)
        S[192 + l] = w2;     // xrs[64..128)
    }
    // ---- phase 3f: cav matvec (6->16, four lane groups) ----
    {
        int c = l & 15, g = l >> 4;
        const float* vec = (g == 0) ? (S + 384) : (g == 1) ? (S + 1432)
                         : (g == 2) ? (S + 392) : (S + 1432);
        const float* Wc = (g < 2) ? Wc1 : Wc2;
        float acc = 0.f;
#pragma unroll
        for (int k = 0; k < 6; ++k)
            acc = __builtin_fmaf(vec[k], Wc[k * 16 + c], acc);
        S[((g & 1) ? 624 : 592) + (g >> 1) * 16 + c] = acc;
    }

    // ---- phase 3g: lanes layer 1 + road gather ----
    {
        float acc = bl1[l];
        const float4* C4 = (const float4*)(curs + 48);
#pragma unroll 4
        for (int kc = 0; kc < 27; ++kc) {
            float4 x = C4[kc];
            int k = kc * 4;
            acc = __builtin_fmaf(x.x, Wl1[(k + 0) * 64 + l], acc);
            acc = __builtin_fmaf(x.y, Wl1[(k + 1) * 64 + l], acc);
            acc = __builtin_fmaf(x.z, Wl1[(k + 2) * 64 + l], acc);
            acc = __builtin_fmaf(x.w, Wl1[(k + 3) * 64 + l], acc);
        }
        h1l[l] = fmaxf(acc, 0.f);
    }
    if (l < 16) {
        float v = 0.f;
        if (l < 13) {
            int idx;
            if (l < 10) {
                int p = l >> 1, odd = l & 1;
                idx = ((p & 1) ? 175 : 156) + (p >> 1) * 2 + odd;
            } else {
                idx = 169 + l;
            }
            v = curs[idx];
        }
        comb[192 + l] = v;
    }

    // ---- phase 4: GAT output layers + lanes2 ----
    float cv0 = gatOut(S, S + 128, 32, Who, aho, 12.f, l);
    float cv1 = gatOut(S + 592, S + 624, 8, Wco, aco, 8.f, l);
    float cv2;
    {
        float acc = bl2[l];
        const float4* H4 = (const float4*)h1l;
#pragma unroll 4
        for (int kc = 0; kc < 16; ++kc) {
            float4 x = H4[kc];
            int k = kc * 4;
            acc = __builtin_fmaf(x.x, Wl2[(k + 0) * 64 + l], acc);
            acc = __builtin_fmaf(x.y, Wl2[(k + 1) * 64 + l], acc);
            acc = __builtin_fmaf(x.z, Wl2[(k + 2) * 64 + l], acc);
            acc = __builtin_fmaf(x.w, Wl2[(k + 3) * 64 + l], acc);
        }
        cv2 = fmaxf(acc, 0.f);
    }
    comb[l] = cv0;
    comb[64 + l] = cv1;
    comb[128 + l] = cv2;

    // ---- phase 5: final MLP ----
    {
        float acc = bm1[l];
        const float4* C4 = (const float4*)comb;
#pragma unroll 4
        for (int kc = 0; kc < 51; ++kc) {
            float4 x = C4[kc];
            int k = kc * 4;
            acc = __builtin_fmaf(x.x, Wm1[(k + 0) * 64 + l], acc);
            acc = __builtin_fmaf(x.y, Wm1[(k + 1) * 64 + l], acc);
            acc = __builtin_fmaf(x.z, Wm1[(k + 2) * 64 + l], acc);
            acc = __builtin_fmaf(x.w, Wm1[(k + 3) * 64 + l], acc);
        }
        acc = __builtin_fmaf(comb[204], Wm1[204 * 64 + l], acc);
        hm[l] = fmaxf(acc, 0.f);
    }
    {
        float acc = bm2[l];
        const float4* H4 = (const float4*)hm;
#pragma unroll 4
        for (int kc = 0; kc < 16; ++kc) {
            float4 x = H4[kc];
            int k = kc * 4;
            acc = __builtin_fmaf(x.x, Wm2[(k + 0) * 64 + l], acc);
            acc = __builtin_fmaf(x.y, Wm2[(k + 1) * 64 + l], acc);
            acc = __builtin_fmaf(x.z, Wm2[(k + 2) * 64 + l], acc);
            acc = __builtin_fmaf(x.w, Wm2[(k + 3) * 64 + l], acc);
        }
        out[(size_t)b * 64 + l] = fmaxf(acc, 0.f);
    }
}

extern "C" void kernel_launch(void* const* d_in, const int* in_sizes, int n_in,
                              void* d_out, int out_size, void* d_ws, size_t ws_size,
                              hipStream_t stream) {
    const float* obs  = (const float*)d_in[0];
    const float* W_se = (const float*)d_in[1];
    const float* b_se = (const float*)d_in[2];
    const float* W_de = (const float*)d_in[3];
    const float* b_de = (const float*)d_in[4];
    const float* Wh1  = (const float*)d_in[5];
    const float* ah1  = (const float*)d_in[6];
    const float* Wh2  = (const float*)d_in[7];
    const float* ah2  = (const float*)d_in[8];
    const float* Who  = (const float*)d_in[9];
    const float* aho  = (const float*)d_in[10];
    const float* Wc1  = (const float*)d_in[11];
    const float* ac1  = (const float*)d_in[12];
    const float* Wc2  = (const float*)d_in[13];
    const float* ac2  = (const float*)d_in[14];
    const float* Wco  = (const float*)d_in[15];
    const float* aco  = (const float*)d_in[16];
    const float* Wl1  = (const float*)d_in[17];
    const float* bl1  = (const float*)d_in[18];
    const float* Wl2  = (const float*)d_in[19];
    const float* bl2  = (const float*)d_in[20];
    const float* Wm1  = (const float*)d_in[21];
    const float* bm1  = (const float*)d_in[22];
    const float* Wm2  = (const float*)d_in[23];
    const float* bm2  = (const float*)d_in[24];

    int B = in_sizes[0] / 2064;  // 16384
    pred_kernel<<<B / 2, 128, 0, stream>>>(
        obs, W_se, b_se, W_de, b_de, Wh1, ah1, Wh2, ah2, Who, aho,
        Wc1, ac1, Wc2, ac2, Wco, aco, Wl1, bl1, Wl2, bl2, Wm1, bm1, Wm2, bm2,
        (float*)d_out);
}